// Round 1
// 997.468 us; speedup vs baseline: 1.1031x; 1.1031x over previous
//
#include <hip/hip_runtime.h>
#include <cmath>

#define T_STEPS 1000
#define B_SZ    128
#define N_IN    85
#define N_RNN   512
#define N_OUT   33
#define K_PAD   88                      // 85 padded to 88 for float4
#define Y_SIZE  (T_STEPS * B_SZ * N_OUT)   // 4,224,000 floats

// ---------------------------------------------------------------------------
// K0: zero the diag-flag (lives at d_out[0], y-region, overwritten by head)
__global__ void k_zero_flag(int* flag) {
    if (threadIdx.x == 0 && blockIdx.x == 0) *flag = 0;
}

// ---------------------------------------------------------------------------
// K1: verify W_rec (rows 85..596 of W) is diagonal; set flag if not.
__global__ void k_check_diag(const float* __restrict__ W, int* flag) {
    const float* Wr = W + N_IN * N_RNN;
    bool bad = false;
    for (int i = blockIdx.x * blockDim.x + threadIdx.x;
         i < N_RNN * N_RNN; i += gridDim.x * blockDim.x) {
        int r = i >> 9, c = i & (N_RNN - 1);
        float v = Wr[i];
        if (r != c && v != 0.0f) bad = true;
    }
    if (bad) atomicOr(flag, 1);
}

// ---------------------------------------------------------------------------
__device__ __forceinline__ float softplus_f(float g) {
    return fmaxf(g, 0.0f) + __logf(1.0f + __expf(-fabsf(g)));
}

// ---------------------------------------------------------------------------
// K2-fused: diagonal-W_rec scan with the input GEMM fused in.
//   h_t[n] = 0.8*h_{t-1}[n] + 0.2*softplus( x[t]·W_in[:,n] + b[n]
//                                           + noise[t,b,n] + dn*h_{t-1}[n] )
// One thread per (b,n) chain; W_in column in 85 VGPRs (reused 1000x).
// x rows double-buffered in LDS (8 steps/tile), read as broadcast b128.
// noise double-ring rA/rB, 8-deep, unconditional loads (1000 = 125*8).
// Raw s_barrier + lgkmcnt-only drain so global prefetch stays in flight
// across tile boundaries (NOT __syncthreads: its vmcnt(0) drain would
// serialize the pipeline every 8 steps).
// Eliminates the 524 MB G round-trip of the old precompute+scan pair and
// provides ~176 cy/step of independent FMA work to hide load latency.
__global__ __launch_bounds__(128) void k_scan_fused(
        const float* __restrict__ x, const float* __restrict__ W,
        const float* __restrict__ bias, const float* __restrict__ noise,
        float* __restrict__ H, const int* __restrict__ flag) {
    if (*flag != 0) return;                    // general path handles it
    const int tid = threadIdx.x;
    const int b   = blockIdx.x >> 2;                   // 0..127
    const int n   = ((blockIdx.x & 3) << 7) + tid;     // 0..511

    // W_in column n into registers; pads zero so pad*pad = 0 (never NaN).
    float wcol[K_PAD];
    #pragma unroll
    for (int k = 0; k < N_IN; ++k) wcol[k] = W[k * N_RNN + n];
    wcol[85] = 0.f; wcol[86] = 0.f; wcol[87] = 0.f;
    const float dn = W[(N_IN + n) * N_RNN + n];
    const float bn = bias[n];

    __shared__ __align__(16) float xs[2][8][K_PAD];    // 5632 B double buffer
    const int row = tid >> 4;      // 0..7   (t-row within 8-step tile)
    const int l16 = tid & 15;      // 16 threads cooperate per row

    const size_t strT = (size_t)B_SZ * N_RNN;          // 65536
    const float* np = noise + (size_t)b * N_RNN + n;
    float*       hp = H     + (size_t)b * N_RNN + n;

    float rA[8], rB[8], xr[6];
    float h = 0.0f;

    // cooperative x-row load for the tile starting at t0 (into regs)
    auto XLD = [&](int t0) {
        const int t = t0 + row;
        const float* xrow = x + ((size_t)t * B_SZ + b) * N_IN;
        #pragma unroll
        for (int j = 0; j < 6; ++j) {
            const int k = l16 + 16 * j;
            xr[j] = (t < T_STEPS && k < N_IN) ? xrow[k] : 0.0f;
        }
    };
    auto XST = [&](int buf) {
        #pragma unroll
        for (int j = 0; j < 6; ++j) {
            const int k = l16 + 16 * j;
            if (k < K_PAD) xs[buf][row][k] = xr[j];
        }
    };
    auto pref8 = [&](float (&ring)[8], int t0) {
        #pragma unroll
        for (int u = 0; u < 8; ++u) ring[u] = np[(size_t)(t0 + u) * strT];
    };
    auto consume8 = [&](float (&ring)[8], int t0, int buf) {
        #pragma unroll
        for (int u = 0; u < 8; ++u) {
            const float4* xv4 = (const float4*)(&xs[buf][u][0]);
            float a0 = 0.f, a1 = 0.f, a2 = 0.f, a3 = 0.f;   // 4 chains: ILP
            #pragma unroll
            for (int k4 = 0; k4 < K_PAD / 4; ++k4) {
                const float4 xv = xv4[k4];                  // LDS broadcast
                a0 = fmaf(xv.x, wcol[4 * k4 + 0], a0);
                a1 = fmaf(xv.y, wcol[4 * k4 + 1], a1);
                a2 = fmaf(xv.z, wcol[4 * k4 + 2], a2);
                a3 = fmaf(xv.w, wcol[4 * k4 + 3], a3);
            }
            const float g = ((a0 + a1) + (a2 + a3)) + (bn + ring[u]) + dn * h;
            h = 0.8f * h + 0.2f * softplus_f(g);
            hp[(size_t)(t0 + u) * strT] = h;
        }
    };

    // ---- prologue: noise tile 0 -> rA; x tile 0 -> LDS[0]; x tile 1 -> regs
    pref8(rA, 0);
    XLD(0); XST(0);
    XLD(8);
    asm volatile("s_waitcnt lgkmcnt(0)" ::: "memory");
    __builtin_amdgcn_s_barrier();
    __builtin_amdgcn_sched_barrier(0);

    int cur = 0;
    // blocks 0..123 in pairs (static ring parity: even->rA, odd->rB)
    #pragma unroll 1
    for (int tb2 = 0; tb2 < 62; ++tb2) {
        const int bb = tb2 << 1;
        // -- even tile bb: consume rA / xs[cur]; prefetch noise bb+1, x bb+2
        pref8(rB, (bb + 1) << 3);
        consume8(rA, bb << 3, cur);
        XST(cur ^ 1);                         // stage x tile bb+1
        XLD((bb + 2) << 3);                   // issue x loads tile bb+2
        asm volatile("s_waitcnt lgkmcnt(0)" ::: "memory");
        __builtin_amdgcn_s_barrier();
        __builtin_amdgcn_sched_barrier(0);
        cur ^= 1;
        // -- odd tile bb+1: consume rB / xs[cur]; prefetch noise bb+2, x bb+3
        pref8(rA, (bb + 2) << 3);             // max t0 = 124*8 = 992, valid
        consume8(rB, (bb + 1) << 3, cur);
        XST(cur ^ 1);
        XLD((bb + 3) << 3);                   // t-guard masks tile 125
        asm volatile("s_waitcnt lgkmcnt(0)" ::: "memory");
        __builtin_amdgcn_s_barrier();
        __builtin_amdgcn_sched_barrier(0);
        cur ^= 1;
    }
    // ---- final tile 124 (even -> rA), t = 992..999, no prefetch
    consume8(rA, 992, cur);
}

// ---------------------------------------------------------------------------
// K2b: G precompute — ONLY for the general (non-diagonal W_rec) fallback.
__global__ __launch_bounds__(256) void k_precompute(
        const float* __restrict__ x, const float* __restrict__ W,
        const float* __restrict__ bias, const float* __restrict__ noise,
        float* __restrict__ G, const int* __restrict__ flag) {
    if (*flag == 0) return;                 // fused fast path covers diag W
    __shared__ float xsh[128 * K_PAD];      // 45,056 B
    const int tid = threadIdx.x;
    const int n   = ((blockIdx.x & 1) << 8) + tid;
    const int r0  = (blockIdx.x >> 1) << 7;

    float wcol[K_PAD];
    #pragma unroll
    for (int k = 0; k < N_IN; ++k) wcol[k] = W[k * N_RNN + n];
    wcol[85] = 0.f; wcol[86] = 0.f; wcol[87] = 0.f;

    const float* xsrc = x + (size_t)r0 * N_IN;
    for (int i = tid; i < 128 * K_PAD; i += 256) {
        const int r = i / K_PAD;
        const int k = i - r * K_PAD;
        xsh[i] = (k < N_IN) ? xsrc[r * N_IN + k] : 0.0f;
    }
    const float bn = bias[n];
    __syncthreads();

    for (int rb = 0; rb < 16; ++rb) {
        const int rbase = rb << 3;
        const size_t gbase = (size_t)(r0 + rbase) * N_RNN + n;
        float npv[8];
        #pragma unroll
        for (int rr = 0; rr < 8; ++rr) npv[rr] = noise[gbase + (size_t)rr * N_RNN];
        float acc[8] = {0.f, 0.f, 0.f, 0.f, 0.f, 0.f, 0.f, 0.f};
        #pragma unroll
        for (int k4 = 0; k4 < K_PAD / 4; ++k4) {
            const float w0 = wcol[4 * k4 + 0];
            const float w1 = wcol[4 * k4 + 1];
            const float w2 = wcol[4 * k4 + 2];
            const float w3 = wcol[4 * k4 + 3];
            #pragma unroll
            for (int rr = 0; rr < 8; ++rr) {
                const float4 xv = *(const float4*)&xsh[(rbase + rr) * K_PAD + 4 * k4];
                acc[rr] = fmaf(xv.x, w0, acc[rr]);
                acc[rr] = fmaf(xv.y, w1, acc[rr]);
                acc[rr] = fmaf(xv.z, w2, acc[rr]);
                acc[rr] = fmaf(xv.w, w3, acc[rr]);
            }
        }
        #pragma unroll
        for (int rr = 0; rr < 8; ++rr) {
            G[gbase + (size_t)rr * N_RNN] = acc[rr] + bn + npv[rr];
        }
    }
}

// ---------------------------------------------------------------------------
// K3b: general W_rec fallback (block-per-b matvec). Exits immediately when
// the diagonal fast path applies.
__global__ __launch_bounds__(512) void k_scan_general(const float* __restrict__ W,
                                                      float* __restrict__ GH,
                                                      const int* __restrict__ flag) {
    if (*flag == 0) return;
    const int b = blockIdx.x;      // 128 blocks
    const int n = threadIdx.x;     // 512 threads
    const int strideT = B_SZ * N_RNN;
    float* base = GH + b * N_RNN + n;
    float h = 0.0f;
    __shared__ float hs[N_RNN];
    const float* Wr = W + N_IN * N_RNN;
    for (int t = 0; t < T_STEPS; ++t) {
        hs[n] = h;
        __syncthreads();
        float g = base[t * strideT];
        for (int k = 0; k < N_RNN; ++k) {
            g = fmaf(hs[k], Wr[k * N_RNN + n], g);
        }
        const float sp = softplus_f(g);
        h = 0.8f * h + 0.2f * sp;
        base[t * strideT] = h;
        __syncthreads();
    }
}

// ---------------------------------------------------------------------------
// K4: y[row,o] = sigmoid(sum_n h[row,n]*W_out[n,o] + b_out[o])
__global__ __launch_bounds__(256) void k_head(const float* __restrict__ hbase,
                                              const float* __restrict__ Wout,
                                              const float* __restrict__ bout,
                                              float* __restrict__ y) {
    __shared__ float ws[N_RNN][36];   // stride 36 keeps float4 rows 16B-aligned
    __shared__ float bs[64];
    const int tid = threadIdx.x;
    for (int i = tid; i < N_RNN * N_OUT; i += 256) {
        int k = i / N_OUT;
        int o = i - k * N_OUT;
        ws[k][o] = Wout[i];
    }
    if (tid < N_OUT) bs[tid] = bout[tid];
    __syncthreads();

    const int row = blockIdx.x * 256 + tid;      // exactly 128000 rows
    const float* hr = hbase + (size_t)row * N_RNN;
    float acc[N_OUT];
    #pragma unroll
    for (int o = 0; o < N_OUT; ++o) acc[o] = bs[o];

    for (int k4 = 0; k4 < N_RNN / 4; ++k4) {
        const float4 hv = *(const float4*)(hr + 4 * k4);
        const float* w0 = &ws[4 * k4][0];
        #pragma unroll
        for (int j = 0; j < 4; ++j) {
            const float hx = (j == 0) ? hv.x : (j == 1) ? hv.y : (j == 2) ? hv.z : hv.w;
            const float4* wr = (const float4*)(w0 + j * 36);
            #pragma unroll
            for (int oo = 0; oo < 8; ++oo) {
                const float4 wv = wr[oo];
                acc[4 * oo + 0] = fmaf(hx, wv.x, acc[4 * oo + 0]);
                acc[4 * oo + 1] = fmaf(hx, wv.y, acc[4 * oo + 1]);
                acc[4 * oo + 2] = fmaf(hx, wv.z, acc[4 * oo + 2]);
                acc[4 * oo + 3] = fmaf(hx, wv.w, acc[4 * oo + 3]);
            }
            acc[32] = fmaf(hx, w0[j * 36 + 32], acc[32]);
        }
    }
    float* yr = y + (size_t)row * N_OUT;
    #pragma unroll
    for (int o = 0; o < N_OUT; ++o) {
        yr[o] = 1.0f / (1.0f + __expf(-acc[o]));
    }
}

// ---------------------------------------------------------------------------
extern "C" void kernel_launch(void* const* d_in, const int* in_sizes, int n_in,
                              void* d_out, int out_size, void* d_ws, size_t ws_size,
                              hipStream_t stream) {
    const float* x     = (const float*)d_in[0];  // [1000,128,85]
    const float* W     = (const float*)d_in[1];  // [597,512]
    const float* bias  = (const float*)d_in[2];  // [512]
    const float* Wout  = (const float*)d_in[3];  // [512,33]
    const float* bout  = (const float*)d_in[4];  // [33]
    const float* noise = (const float*)d_in[5];  // [1000,128,512]

    float* y  = (float*)d_out;          // y_hat region [1000,128,33]
    float* GH = y + Y_SIZE;             // h region [1000,128,512]
    int* flag = (int*)d_out;            // aliases y[0]; head overwrites it last

    k_zero_flag<<<1, 64, 0, stream>>>(flag);
    k_check_diag<<<256, 256, 0, stream>>>(W, flag);
    k_scan_fused<<<512, 128, 0, stream>>>(x, W, bias, noise, GH, flag);
    k_precompute<<<2000, 256, 0, stream>>>(x, W, bias, noise, GH, flag);  // flag!=0 only
    k_scan_general<<<128, 512, 0, stream>>>(W, GH, flag);                 // flag!=0 only
    k_head<<<500, 256, 0, stream>>>(GH, Wout, bout, y);
}